// Round 10
// baseline (139.892 us; speedup 1.0000x reference)
//
#include <hip/hip_runtime.h>
#include <math.h>

// TTrain log-contraction, R10: 32x32x16 MFMA retile.
// R8/R9 post-mortem: stage1 pinned at ~62us / MfmaUtil 48% regardless of
// VALU/scalar micro-structure -> cut matrix-pipe work itself.
// 32x32x16_bf16: 32kFLOP/8.07cyc vs 16kFLOP/4.85cyc (+17% rate), and
// 16 MFMA/product instead of 32.
//
// Zero-shuffle feedback, 32x32 version: C/D layout col=lane&31,
// row=(reg&3)+8(reg>>2)+4(lane>>5); B layout n=lane&31, k=8(lane>>5)+j.
// Feeding packed C reg-group G=Kb&1 of tile I'=Kb>>1 as B frag of K-slice
// Kb presents M~=P_phi*M with phi32(16Kb+8h+j)=16Kb+(j&3)+8(j>>2)+4h,
// baked into A'/Binit tables. Per-product transform = 32 in-lane v_perm.
// Renorm every 8 products (mathematically identical to per-step inf-norm).
// Structure: 16 chunks of 64/batch, 2048 waves @ 2/SIMD, double-A-buffer,
// 3 kernels (R7: per-WG device fences ≫ kernel-boundary coherence).

#define TT_S 1024
#define TT_D 64
#define NCHUNK 16
#define CLEN 64            // NCHUNK * CLEN == TT_S

typedef __attribute__((ext_vector_type(8))) short short8;     // 8 bf16
typedef __attribute__((ext_vector_type(4))) float float4v;
typedef __attribute__((ext_vector_type(16))) float float16v;  // 32x32 C/D
typedef __attribute__((ext_vector_type(4))) unsigned uint4v;
typedef __attribute__((ext_vector_type(2))) unsigned uint2v;

static __device__ __forceinline__ short8 as_short8(uint4v u) {
    union { uint4v u; short8 s; } x; x.u = u; return x.s;
}

// ---------- prep: phi32-permuted A' table + phi32-row-permuted Binit ----
// A frag f=4I+Kb (I<2,Kb<4): lane(nh=l&31,h=l>>5) holds
//   W[32I+nh][16Kb + (j&3)+8*(j>>2)+4h], j=0..7
// Binit frag f=2Kb+J (J<2): lane holds W[16Kb+(j&3)+8*(j>>2)+4h][32J+nh]
// 4 waves/block: wave r builds frags 4r..4r+3 of the [A(8),B(8)] list.
__global__ __launch_bounds__(256) void tt_prep(
    const float* __restrict__ core, short* __restrict__ tblA,
    short* __restrict__ tblBt)
{
    const int x = blockIdx.x;
    const int l = threadIdx.x & 63, r = threadIdx.x >> 6;
    const int nh = l & 31, h = l >> 5;
    const float* W = core + x * 4096;

    #pragma unroll
    for (int fi = 0; fi < 4; ++fi) {
        const int f = 4 * r + fi;          // 0..15
        short8 v;
        short* dst;
        if (f < 8) {                        // A frag: I=f>>2, Kb=f&3
            const int I = f >> 2, Kb = f & 3;
            const int row = 32 * I + nh;
            #pragma unroll
            for (int j = 0; j < 8; ++j) {
                const int col = 16 * Kb + (j & 3) + 8 * (j >> 2) + 4 * h;
                v[j] = (short)(__float_as_uint(W[row * 64 + col]) >> 16);
            }
            dst = tblA + ((size_t)(x * 8 + f) * 64 + l) * 8;
        } else {                            // B frag: fb=f-8, Kb=fb>>1, J=fb&1
            const int fb = f - 8, Kb = fb >> 1, J = fb & 1;
            const int col = 32 * J + nh;
            #pragma unroll
            for (int j = 0; j < 8; ++j) {
                const int row = 16 * Kb + (j & 3) + 8 * (j >> 2) + 4 * h;
                v[j] = (short)(__float_as_uint(W[row * 64 + col]) >> 16);
            }
            dst = tblBt + ((size_t)(x * 8 + fb) * 64 + l) * 8;
        }
        *(short8*)dst = v;
    }
}

// ---------- stage 1: one wave per chunk of 64 matrices ----------
__global__ __launch_bounds__(64, 2) void tt_stage1(
    const int* __restrict__ X, const short* __restrict__ tblA,
    const short* __restrict__ tblBt, short* __restrict__ PT,
    float* __restrict__ ln1)
{
    const int w = blockIdx.x;
    const int b = w >> 4, chunk = w & 15;
    const int l = threadIdx.x, nh = l & 31, h = l >> 5;

    // all 64 chunk indices, lane-parallel; per-product via v_readlane
    const int xv = X[b * TT_S + chunk * CLEN + l];
    #define XT(t) __builtin_amdgcn_readlane(xv, (t))

    const float16v zero16 = {0,0,0,0,0,0,0,0,0,0,0,0,0,0,0,0};
    float16v acc[2][2];
    short8 A0[8], A1[8];
    float logn = 0.f;

    #define PK(hi, lo) __builtin_amdgcn_perm(__float_as_uint(hi),             \
                                             __float_as_uint(lo), 0x07060302u)

    #define LOAD_FRAGS(DST, TBL, XIDX)                                        \
    {   const short8* p_ = (const short8*)((TBL) + (size_t)(XIDX) * 4096) + l; \
        _Pragma("unroll")                                                     \
        for (int f_ = 0; f_ < 8; ++f_) (DST)[f_] = p_[f_ * 64]; }

    // first product: B from phi-row-permuted table
    #define MFMA_TBL(ABUF, BBUF)                                              \
        _Pragma("unroll")                                                     \
        for (int I_ = 0; I_ < 2; ++I_)                                        \
            _Pragma("unroll")                                                 \
            for (int J_ = 0; J_ < 2; ++J_) {                                  \
                float16v c_ = zero16;                                         \
                _Pragma("unroll")                                             \
                for (int Kb_ = 0; Kb_ < 4; ++Kb_)                             \
                    c_ = __builtin_amdgcn_mfma_f32_32x32x16_bf16(             \
                        (ABUF)[I_ * 4 + Kb_], (BBUF)[Kb_ * 2 + J_],           \
                        c_, 0, 0, 0);                                         \
                acc[I_][J_] = c_;                                             \
            }

    // feedback product, column-interleaved: pack column J's 4 B frags
    // (reads acc[*][J] only), then the 8 MFMAs that rewrite acc[*][J].
    #define PROD(ABUF)                                                        \
        _Pragma("unroll")                                                     \
        for (int J_ = 0; J_ < 2; ++J_) {                                      \
            short8 bb_[4];                                                    \
            _Pragma("unroll")                                                 \
            for (int Kb_ = 0; Kb_ < 4; ++Kb_) {                               \
                const int I2_ = Kb_ >> 1, g_ = 8 * (Kb_ & 1);                 \
                uint4v u_;                                                    \
                u_[0] = PK(acc[I2_][J_][g_ + 1], acc[I2_][J_][g_ + 0]);       \
                u_[1] = PK(acc[I2_][J_][g_ + 3], acc[I2_][J_][g_ + 2]);       \
                u_[2] = PK(acc[I2_][J_][g_ + 5], acc[I2_][J_][g_ + 4]);       \
                u_[3] = PK(acc[I2_][J_][g_ + 7], acc[I2_][J_][g_ + 6]);       \
                bb_[Kb_] = as_short8(u_);                                     \
            }                                                                 \
            _Pragma("unroll")                                                 \
            for (int I_ = 0; I_ < 2; ++I_) {                                  \
                float16v c_ = zero16;                                         \
                _Pragma("unroll")                                             \
                for (int Kb_ = 0; Kb_ < 4; ++Kb_)                             \
                    c_ = __builtin_amdgcn_mfma_f32_32x32x16_bf16(             \
                        (ABUF)[I_ * 4 + Kb_], bb_[Kb_], c_, 0, 0, 0);         \
                acc[I_][J_] = c_;                                             \
            }                                                                 \
        }

    #define RENORM()                                                          \
    {   float Z_ = 0.f;                                                       \
        _Pragma("unroll")                                                     \
        for (int I_ = 0; I_ < 2; ++I_)                                        \
            _Pragma("unroll")                                                 \
            for (int J_ = 0; J_ < 2; ++J_)                                    \
                _Pragma("unroll")                                             \
                for (int r_ = 0; r_ < 16; ++r_)                               \
                    Z_ = fmaxf(Z_, fabsf(acc[I_][J_][r_]));                   \
        _Pragma("unroll")                                                     \
        for (int m_ = 32; m_; m_ >>= 1) Z_ = fmaxf(Z_, __shfl_xor(Z_, m_));   \
        logn += logf(Z_);                                                     \
        const float rZ_ = 1.0f / Z_;                                          \
        _Pragma("unroll")                                                     \
        for (int I_ = 0; I_ < 2; ++I_)                                        \
            _Pragma("unroll")                                                 \
            for (int J_ = 0; J_ < 2; ++J_)                                    \
                _Pragma("unroll")                                             \
                for (int r_ = 0; r_ < 16; ++r_) acc[I_][J_][r_] *= rZ_; }

    // init + first product
    {
        short8 Bt[8];
        LOAD_FRAGS(Bt, tblBt, XT(CLEN - 1))
        LOAD_FRAGS(A0, tblA, XT(CLEN - 2))
        LOAD_FRAGS(A1, tblA, XT(CLEN - 3))
        MFMA_TBL(A0, Bt)
    }
    LOAD_FRAGS(A0, tblA, XT(CLEN - 4))

    #pragma unroll 1
    for (int it = 0; it < 31; ++it) {
        // product 2it+2 (consumes A1), refill A1
        PROD(A1)
        {
            const int tn = 59 - 2 * it;
            LOAD_FRAGS(A1, tblA, XT(tn < 0 ? 0 : tn))
        }
        // product 2it+3 (consumes A0), refill A0
        if (((2 * it + 2) & 7) == 0) RENORM()
        PROD(A0)
        {
            const int tn = 58 - 2 * it;
            LOAD_FRAGS(A0, tblA, XT(tn < 0 ? 0 : tn))
        }
    }

    // final renorm + write P (bf16, col-major: PT[col*64+row]) + log-norm
    {
        float Z = 0.f;
        #pragma unroll
        for (int I = 0; I < 2; ++I)
            #pragma unroll
            for (int J = 0; J < 2; ++J)
                #pragma unroll
                for (int r = 0; r < 16; ++r) Z = fmaxf(Z, fabsf(acc[I][J][r]));
        #pragma unroll
        for (int m = 32; m; m >>= 1) Z = fmaxf(Z, __shfl_xor(Z, m));
        logn += logf(Z);
        const float rZ = 1.0f / Z;
        short* base = PT + (size_t)w * 4096;
        #pragma unroll
        for (int I = 0; I < 2; ++I)
            #pragma unroll
            for (int J = 0; J < 2; ++J) {
                float16v v = acc[I][J];
                #pragma unroll
                for (int r = 0; r < 16; ++r) v[r] *= rZ;
                #pragma unroll
                for (int rg = 0; rg < 4; ++rg) {
                    uint2v dd;
                    dd[0] = PK(v[4 * rg + 1], v[4 * rg + 0]);
                    dd[1] = PK(v[4 * rg + 3], v[4 * rg + 2]);
                    // rows 8*rg+4h+{0..3} of band 32I, col 32J+nh
                    *(uint2v*)(base + (32 * J + nh) * 64 + 32 * I
                               + 8 * rg + 4 * h) = dd;
                }
            }
        if (l == 0) ln1[w] = logn;
    }
    #undef LOAD_FRAGS
    #undef MFMA_TBL
    #undef PROD
    #undef RENORM
    #undef PK
    #undef XT
}

// ---------- stage 2: combine NCHUNK chunk matrices per batch ----------
__global__ __launch_bounds__(64, 1) void tt_stage2(
    const short* __restrict__ PT, const float* __restrict__ ln1,
    const float* __restrict__ lb, const float* __restrict__ rb,
    float* __restrict__ out)
{
    __shared__ float cb[64];
    const int b = blockIdx.x, j = threadIdx.x;

    float c = lb[j];
    float Z = fabsf(c);
    #pragma unroll
    for (int m = 32; m; m >>= 1) Z = fmaxf(Z, __shfl_xor(Z, m));
    float logn = logf(Z);
    c *= (1.0f / Z);

    float ln = (j < NCHUNK) ? ln1[b * NCHUNK + j] : 0.f;
    #pragma unroll
    for (int m = 32; m; m >>= 1) ln += __shfl_xor(ln, m);
    logn += ln;

    // lane j's column of P_k: 64 bf16 contiguous (PT col-major)
    const short* base = PT + (size_t)b * NCHUNK * 4096 + j * 64;

    short8 bufA[8], bufB[8];
    #pragma unroll
    for (int f = 0; f < 8; ++f) bufA[f] = ((const short8*)base)[f];

    #define S2_STEP(BUF)                                                      \
    {                                                                         \
        cb[j] = c;                                                            \
        asm volatile("s_waitcnt lgkmcnt(0)" ::: "memory");                    \
        float a0 = 0.f, a1 = 0.f, a2 = 0.f, a3 = 0.f;                         \
        _Pragma("unroll")                                                     \
        for (int f = 0; f < 8; ++f) {                                         \
            union { short8 s; uint4v u; } uu; uu.s = (BUF)[f];                \
            const float4v cv0 = *(const float4v*)(cb + 8 * f);                \
            const float4v cv1 = *(const float4v*)(cb + 8 * f + 4);            \
            a0 = fmaf(cv0[0], __uint_as_float(uu.u[0] << 16), a0);            \
            a1 = fmaf(cv0[1], __uint_as_float(uu.u[0] & 0xffff0000u), a1);    \
            a2 = fmaf(cv0[2], __uint_as_float(uu.u[1] << 16), a2);            \
            a3 = fmaf(cv0[3], __uint_as_float(uu.u[1] & 0xffff0000u), a3);    \
            a0 = fmaf(cv1[0], __uint_as_float(uu.u[2] << 16), a0);            \
            a1 = fmaf(cv1[1], __uint_as_float(uu.u[2] & 0xffff0000u), a1);    \
            a2 = fmaf(cv1[2], __uint_as_float(uu.u[3] << 16), a2);            \
            a3 = fmaf(cv1[3], __uint_as_float(uu.u[3] & 0xffff0000u), a3);    \
        }                                                                     \
        float cn = (a0 + a1) + (a2 + a3);                                     \
        float Zl = fabsf(cn);                                                 \
        _Pragma("unroll")                                                     \
        for (int m = 32; m; m >>= 1) Zl = fmaxf(Zl, __shfl_xor(Zl, m));       \
        logn += logf(Zl);                                                     \
        c = cn * (1.0f / Zl);                                                 \
    }

    #pragma unroll 1
    for (int k = 0; k < NCHUNK; k += 2) {
        {   const short8* p = (const short8*)(base + (size_t)(k + 1) * 4096);
            #pragma unroll
            for (int f = 0; f < 8; ++f) bufB[f] = p[f];
        }
        asm volatile("" ::: "memory");
        S2_STEP(bufA)
        {   const int kn = (k + 2 < NCHUNK) ? (k + 2) : (NCHUNK - 1);
            const short8* p = (const short8*)(base + (size_t)kn * 4096);
            #pragma unroll
            for (int f = 0; f < 8; ++f) bufA[f] = p[f];
        }
        asm volatile("" ::: "memory");
        S2_STEP(bufB)
    }
    #undef S2_STEP

    float dot = c * rb[j];
    #pragma unroll
    for (int m = 32; m; m >>= 1) dot += __shfl_xor(dot, m);
    if (j == 0) out[b] = 2.0f * (logn + logf(fabsf(dot)));
}

// ---------------- fallback (R2 kernel) if d_ws is too small ----------------
__global__ __launch_bounds__(256) void tt_transpose(
    const float* __restrict__ core, float* __restrict__ coreT)
{
    __shared__ float tile[64][65];
    const int x = blockIdx.x;
    const float* src = core + x * 4096;
    float* dst = coreT + x * 4096;
    const int r0 = threadIdx.x >> 6, cc = threadIdx.x & 63;
    #pragma unroll
    for (int k = 0; k < 16; ++k) tile[r0 + 4 * k][cc] = src[(r0 + 4 * k) * 64 + cc];
    __syncthreads();
    #pragma unroll
    for (int k = 0; k < 16; ++k) dst[(r0 + 4 * k) * 64 + cc] = tile[cc][r0 + 4 * k];
}

__global__ __launch_bounds__(64, 1) void ttrain_chain2(
    const int* __restrict__ X, const float* __restrict__ coreT,
    const float* __restrict__ lb, const float* __restrict__ rb,
    float* __restrict__ out)
{
    __shared__ float cbuf[2][64];
    const int b = blockIdx.x, j = threadIdx.x;
    const int* Xrow = X + b * TT_S;
    float c = lb[j];
    float Z = fabsf(c);
    #pragma unroll
    for (int m = 32; m; m >>= 1) Z = fmaxf(Z, __shfl_xor(Z, m));
    float logn = logf(Z);
    c *= (1.0f / Z);
    const float* colbase = coreT + j * 64;
    int xs_cur = Xrow[j];
    int xs_nxt = Xrow[64 + j];
    float4 wA[16], wB[16];
    {
        const int x0 = Xrow[0];
        const float4* p = (const float4*)(colbase + x0 * 4096);
        #pragma unroll
        for (int k = 0; k < 16; ++k) wA[k] = p[k];
    }
    #define TT_STEP(WCUR, WNXT, SLOT, XNEXT, T)                              \
    {                                                                        \
        cbuf[SLOT][j] = c;                                                   \
        {                                                                    \
            const float4* pre = (const float4*)(colbase + (XNEXT) * 4096);   \
            _Pragma("unroll")                                                \
            for (int k = 0; k < 16; ++k) WNXT[k] = pre[k];                   \
        }                                                                    \
        asm volatile("s_waitcnt lgkmcnt(0)" ::: "memory");                   \
        float a0 = 0.f, a1 = 0.f, a2 = 0.f, a3 = 0.f;                        \
        const float4* cb2 = (const float4*)cbuf[SLOT];                       \
        _Pragma("unroll")                                                    \
        for (int k = 0; k < 16; ++k) {                                       \
            float4 cv = cb2[k];                                              \
            a0 = fmaf(cv.x, WCUR[k].x, a0);                                  \
            a1 = fmaf(cv.y, WCUR[k].y, a1);                                  \
            a2 = fmaf(cv.z, WCUR[k].z, a2);                                  \
            a3 = fmaf(cv.w, WCUR[k].w, a3);                                  \
        }                                                                    \
        float cn = (a0 + a1) + (a2 + a3);                                    \
        if (((T) & 7) == 7) {                                                \
            float Zl = fabsf(cn);                                            \
            _Pragma("unroll")                                                \
            for (int m = 32; m; m >>= 1) Zl = fmaxf(Zl, __shfl_xor(Zl, m));  \
            logn += logf(Zl);                                                \
            cn *= (1.0f / Zl);                                               \
        }                                                                    \
        c = cn;                                                              \
    }
    for (int tc = 0; tc < TT_S; tc += 64) {
        #pragma unroll 1
        for (int u = 0; u < 64; u += 2) {
            const int x1 = __builtin_amdgcn_readlane(xs_cur, u + 1);
            TT_STEP(wA, wB, 0, x1, tc + u)
            const int src2 = (u + 2 < 64) ? xs_cur : xs_nxt;
            const int x2 = __builtin_amdgcn_readlane(src2, (u + 2) & 63);
            TT_STEP(wB, wA, 1, x2, tc + u + 1)
        }
        xs_cur = xs_nxt;
        const int nc = tc + 128;
        xs_nxt = Xrow[((nc < TT_S) ? nc : 0) + j];
    }
    #undef TT_STEP
    float dot = c * rb[j];
    #pragma unroll
    for (int m = 32; m; m >>= 1) dot += __shfl_xor(dot, m);
    if (j == 0) out[b] = 2.0f * (logn + logf(fabsf(dot)));
}

extern "C" void kernel_launch(void* const* d_in, const int* in_sizes, int n_in,
                              void* d_out, int out_size, void* d_ws, size_t ws_size,
                              hipStream_t stream) {
    const int*   X    = (const int*)d_in[0];    // [B, S] int32
    const float* core = (const float*)d_in[1];  // [d, D, D] fp32
    const float* lb   = (const float*)d_in[2];  // [D]
    const float* rb   = (const float*)d_in[3];  // [D]
    float* out = (float*)d_out;                 // [B]

    const int B = in_sizes[0] / TT_S;
    const size_t tblBytes = (size_t)64 * 8 * 64 * 8 * sizeof(short);     // 512KB each
    const size_t ptBytes  = (size_t)B * NCHUNK * 4096 * sizeof(short);   // 16MB @B=128
    const size_t lnBytes  = (size_t)B * NCHUNK * sizeof(float);
    const size_t need = 2 * tblBytes + ptBytes + lnBytes;

    if (ws_size >= need) {
        char* w = (char*)d_ws;
        short* tblA  = (short*)w;
        short* tblBt = (short*)(w + tblBytes);
        short* PT    = (short*)(w + 2 * tblBytes);
        float* ln1   = (float*)(w + 2 * tblBytes + ptBytes);
        tt_prep<<<64, 256, 0, stream>>>(core, tblA, tblBt);
        tt_stage1<<<B * NCHUNK, 64, 0, stream>>>(X, tblA, tblBt, PT, ln1);
        tt_stage2<<<B, 64, 0, stream>>>(PT, ln1, lb, rb, out);
    } else if (ws_size >= (size_t)64 * 4096 * sizeof(float)) {
        float* coreT = (float*)d_ws;
        tt_transpose<<<64, 256, 0, stream>>>(core, coreT);
        ttrain_chain2<<<B, TT_D, 0, stream>>>(X, coreT, lb, rb, out);
    }
}